// Round 1
// 118.521 us; speedup vs baseline: 1.0074x; 1.0074x over previous
//
#include <hip/hip_runtime.h>
#include <hip/hip_bf16.h>
#include <math.h>

// Dtype model (pinned R0-R4): float inputs f32; edge_index int32; d_out read
// as f32: chunk0 = pred f32[0:393216], chunk1 = yg f32[393216:786432]; np
// reference computed from bf16-cast inputs -> bf16 intermediates safe.
//
// R7: register spills kill. R9: strided us8 LDS reads = bank-conflict storm.
// R10: P[64x64]@X MFMA aggregation + transposed xs + prepacked W^T -> 127us.
// R11: fuse both GAT layers into one per-graph kernel, 5 launches -> 3. 119us.
// R12 (this): (a) attention projections folded into the xl GEMMs as extra
// output columns (L1: free pad cols 400..407; L2: one extra tile on wave 0,
// W2t extended to 528 rows) -> both serial logits phases deleted; (b) fw1/fw2
// prepacked transposed bf16 + h2 stored transposed-by-node (h2t[k][b][c]) ->
// mlp reads A/B frags straight from global (L2), no LDS staging, 1 barrier.
//
// Race check: As2 k-pad zeroing must stay AFTER the L1 GEMM consumed As1
// (LDA1 reads overlap LDA2 pad addresses) -> stays in softmax spare threads.

#define N_NODES 16384
#define B_GRAPHS 256
#define K_NODES 64
#define DEG 8
#define NHEADS 4
#define C1 100
#define C2 128
#define IN_F 96
#define HID 64
#define OUT_SZ 24
#define PRED_ELEMS (K_NODES * B_GRAPHS * OUT_SZ)   // 393216

#define W1T_ROWS 448   // 400 cols + 8 logit cols (400..407) padded to 7*64
#define W1T_K    96
#define W2T_ROWS 528   // 512 cols + 8 logit cols (512..519) padded to 33*16
#define W2T_K    128   // 100 padded

using bf16 = __hip_bfloat16;
typedef __attribute__((ext_vector_type(8))) short          frag_ab;  // 8 bf16
typedef __attribute__((ext_vector_type(4))) float          frag_cd;  // 4 f32
typedef unsigned short us8 __attribute__((ext_vector_type(8)));      // 16 B
typedef unsigned short us4 __attribute__((ext_vector_type(4)));      // 8 B

__device__ __forceinline__ float us2f(unsigned short u) {
  return __bfloat162float(__ushort_as_bfloat16(u));
}
__device__ __forceinline__ short f2bf_s(float f) {
  return __builtin_bit_cast(short, __float2bfloat16(f));
}

// ---------------------------------------------------------------------------
// prep: pack W1^T/W2^T (bf16, padded, k-contiguous, + fused attention
// projection columns Ws=W·a_src / Wd=W·a_dst), fw1^T/fw2^T (bf16), and
// yg = float(bf16(y)). All independent -> one kernel.
// ---------------------------------------------------------------------------
#define P1N  (W1T_ROWS * W1T_K)            // 43008
#define P2N  (W2T_ROWS * W2T_K)            // 67584
#define YG4  (PRED_ELEMS / 4)              // 98304
#define FW1N (K_NODES * HID * C2)          // 524288  [k][n<64][kk<128]
#define FW2N (K_NODES * 32 * HID)          // 131072  [k][n<32][kk<64]
#define PREP_TOT (P1N + P2N + YG4 + FW1N + FW2N)   // 864256 = 3376*256

__global__ __launch_bounds__(256)
void prep(const float* __restrict__ W1, const float* __restrict__ W2,
          const float* __restrict__ y,
          const float* __restrict__ as1, const float* __restrict__ ad1,
          const float* __restrict__ as2, const float* __restrict__ ad2,
          const float* __restrict__ fw1, const float* __restrict__ fw2,
          bf16* __restrict__ W1t, bf16* __restrict__ W2t,
          bf16* __restrict__ fw1t, bf16* __restrict__ fw2t,
          float* __restrict__ yg) {
  int idx = blockIdx.x * 256 + threadIdx.x;
  if (idx < P1N) {
    int c = idx / W1T_K, k = idx - c * W1T_K;
    float v = 0.f;
    if (c < 400) {
      v = W1[(size_t)k * 400 + c];
    } else if (c < 408) {
      int h = (c - 400) & 3;
      const float* av = (c < 404) ? as1 : ad1;
      float s = 0.f;
#pragma unroll 4
      for (int q = 0; q < 100; ++q)
        s += W1[(size_t)k * 400 + h * 100 + q] * av[h * 100 + q];
      v = s;
    }
    W1t[idx] = __float2bfloat16(v);
  } else if (idx < P1N + P2N) {
    int i2 = idx - P1N;
    int c = i2 >> 7, kk = i2 & 127;
    float v = 0.f;
    if (c < 512) {
      if (kk < 100) v = W2[(size_t)kk * 512 + c];
    } else if (c < 520 && kk < 100) {
      int h = (c - 512) & 3;
      const float* av = (c < 516) ? as2 : ad2;
      float s = 0.f;
#pragma unroll 4
      for (int q = 0; q < 128; ++q)
        s += W2[(size_t)kk * 512 + h * 128 + q] * av[h * 128 + q];
      v = s;
    }
    W2t[i2] = __float2bfloat16(v);
  } else if (idx < P1N + P2N + YG4) {
    int j = idx - P1N - P2N;
    int i = j * 4;
    float4 v = *(const float4*)(y + i);
    v.x = __bfloat162float(__float2bfloat16(v.x));
    v.y = __bfloat162float(__float2bfloat16(v.y));
    v.z = __bfloat162float(__float2bfloat16(v.z));
    v.w = __bfloat162float(__float2bfloat16(v.w));
    *(float4*)(yg + i) = v;
  } else if (idx < P1N + P2N + YG4 + FW1N) {
    int i4 = idx - (P1N + P2N + YG4);
    int k = i4 >> 13, r = i4 & 8191, n = r >> 7, kk = r & 127;
    fw1t[i4] = __float2bfloat16(fw1[(size_t)k * (C2 * HID) + kk * HID + n]);
  } else {
    int i5 = idx - (P1N + P2N + YG4 + FW1N);
    if (i5 < FW2N) {
      int k = i5 >> 11, r = i5 & 2047, n = r >> 6, kk = r & 63;
      fw2t[i5] = __float2bfloat16(
          (n < OUT_SZ) ? fw2[(size_t)k * (HID * OUT_SZ) + kk * OUT_SZ + n] : 0.f);
    }
  }
}

// ---------------------------------------------------------------------------
// Fused two-layer GAT, one block per graph (grid=256), 512 threads (8 waves).
// LDS (~133 KB): As (A-slab, both layers), xs (xl^T incl. logit rows), Ps.
// L1: stage x -> As(104); xl1+logits = As@W1t -> xs^T (logits in rows
//     400..407); softmax -> Ps (spare threads zero As2 k-pads); agg MFMA ->
//     ELU -> As(136).
// L2: xl2 = As@W2t -> xs^T (wave 0 adds logit tile, rows 512..519); softmax
//     -> Ps (same support, no re-zero); agg MFMA -> h2t global transposed.
// ---------------------------------------------------------------------------
__global__ __launch_bounds__(512)
void gat_fused(const float* __restrict__ x,
               const bf16* __restrict__ W1t, const bf16* __restrict__ W2t,
               const int* __restrict__ esrc,
               const float* __restrict__ b1, const float* __restrict__ b2,
               bf16* __restrict__ h2t) {
  constexpr int LDA1 = IN_F + 8;     // 104 (shorts)
  constexpr int LDA2 = 136;          // layer-2 A stride (K=128 + 8)
  constexpr int LDT  = 72;           // xs/Ps row stride (shorts)

  __shared__ __align__(16) short          As[64 * LDA2];          // 17.4 KB
  __shared__ __align__(16) unsigned short xs[W2T_ROWS * LDT];     // 76.0 KB
  __shared__ __align__(16) short          Ps[NHEADS * 64 * LDT];  // 36.9 KB
  __shared__ float bia1[C1], bia2[C2];
  __shared__ int   edg[K_NODES * DEG];

  const int g = blockIdx.x;
  const int t = threadIdx.x;
  const int wv = t >> 6;
  const int l  = t & 63;
  const int lm = l & 15;
  const int lk = (l >> 4) * 8;
  const int rq = (l >> 4) * 4;

  // ================= phase 0: stage =================
  {
    constexpr int QR = IN_F / 4;     // 24 float4 per row
    for (int idx = t; idx < 64 * QR; idx += 512) {
      int m = idx / QR, q = idx - m * QR;
      const float4 v = *(const float4*)(x + ((size_t)(g * 64 + m) * IN_F + q * 4));
      short* d = &As[m * LDA1 + q * 4];
      d[0] = f2bf_s(v.x); d[1] = f2bf_s(v.y); d[2] = f2bf_s(v.z); d[3] = f2bf_s(v.w);
    }
  }
  if (t < C1) bia1[t] = b1[t];
  else if (t >= 128 && t < 128 + C2) bia2[t - 128] = b2[t - 128];
  if (t < K_NODES * DEG) edg[t] = esrc[g * K_NODES * DEG + t] & (K_NODES - 1);
  for (int idx = t; idx < NHEADS * 64 * LDT / 8; idx += 512)
    *(us8*)&Ps[idx * 8] = (us8)0;
  __syncthreads();

  // ====== L1 phase 1: [xl1 | logits] = As @ W1t -> xs^T (waves 0..6) ======
  if (wv < 7) {
    const int n0 = wv * 64;
    frag_cd acc[4][4] = {};
#pragma unroll
    for (int ks = 0; ks < IN_F; ks += 32) {
      frag_ab b[4];
#pragma unroll
      for (int nt = 0; nt < 4; ++nt)
        b[nt] = *(const frag_ab*)((const short*)W1t +
                                  (size_t)(n0 + nt * 16 + lm) * W1T_K + ks + lk);
#pragma unroll
      for (int mt = 0; mt < 4; ++mt) {
        frag_ab a = *(const frag_ab*)&As[(mt * 16 + lm) * LDA1 + ks + lk];
#pragma unroll
        for (int nt = 0; nt < 4; ++nt)
          acc[mt][nt] = __builtin_amdgcn_mfma_f32_16x16x32_bf16(a, b[nt],
                                                                acc[mt][nt], 0, 0, 0);
      }
    }
#pragma unroll
    for (int mt = 0; mt < 4; ++mt)
#pragma unroll
      for (int nt = 0; nt < 4; ++nt) {
        const int c4 = n0 + nt * 16 + lm;
        us4 o;
#pragma unroll
        for (int r = 0; r < 4; ++r) o[r] = (unsigned short)f2bf_s(acc[mt][nt][r]);
        *(us4*)&xs[c4 * LDT + mt * 16 + rq] = o;
      }
  }
  __syncthreads();

  // ====== L1 phase 2: softmax -> Ps; spare threads zero As2 k-pads ======
  if (t < 256) {
    const int n = t >> 2, h = t & 3;
    const float ad = us2f(xs[(404 + h) * LDT + n]);
    int   sv[9];
    float a[9];
#pragma unroll
    for (int j = 0; j < 8; ++j) sv[j] = edg[n * DEG + j];
    sv[8] = n;
#pragma unroll
    for (int j = 0; j < 9; ++j) {
      float v = us2f(xs[(400 + h) * LDT + sv[j]]) + ad;
      a[j] = (v >= 0.f) ? v : 0.2f * v;       // leaky_relu 0.2
    }
    float m = -1e30f;
#pragma unroll
    for (int j = 0; j < 9; ++j) m = fmaxf(m, a[j]);
    float s = 0.f;
#pragma unroll
    for (int j = 0; j < 9; ++j) { a[j] = __expf(a[j] - m); s += a[j]; }
    const float inv = 1.f / (s + 1e-16f);
    short* prow = &Ps[(h * 64 + n) * LDT];
#pragma unroll
    for (int j = 0; j < 9; ++j) {
      float tw = a[j];
#pragma unroll
      for (int i = 0; i < 9; ++i)
        if (i != j && sv[i] == sv[j]) tw += a[i];
      prow[sv[j]] = f2bf_s(tw * inv);         // idempotent dedupe
    }
  } else {
    // zero As layer-2 k-padding (k = 100..127); As1 is dead here
    for (int i = t - 256; i < 64 * 28; i += 256) {
      int m = i / 28, kk = 100 + (i - m * 28);
      As[m * LDA2 + kk] = 0;
    }
  }
  __syncthreads();

  // ====== L1 phase 3: h1 = 0.25*sum_h P_h @ X_h + bias, ELU -> As2 ======
  {
    const int mw = (wv & 3) * 16;
    const int cg = wv >> 2;
    const int ntb = cg * 4;
    const int nte = (cg == 0) ? 4 : 7;        // NT=7 tiles split 4+3
    frag_cd acc[4] = {};
#pragma unroll
    for (int h = 0; h < NHEADS; ++h)
#pragma unroll
      for (int ks = 0; ks < 64; ks += 32) {
        frag_ab a = *(const frag_ab*)&Ps[(h * 64 + mw + lm) * LDT + ks + lk];
        for (int nt = ntb; nt < nte; ++nt) {
          frag_ab b = *(const frag_ab*)&xs[(h * C1 + nt * 16 + lm) * LDT + ks + lk];
          acc[nt - ntb] = __builtin_amdgcn_mfma_f32_16x16x32_bf16(a, b,
                                                                  acc[nt - ntb], 0, 0, 0);
      }
    }
    for (int nt = ntb; nt < nte; ++nt) {
      const int c = nt * 16 + lm;
      if (c < C1) {
        const float bc = bia1[c];
#pragma unroll
        for (int r = 0; r < 4; ++r) {
          float vv = acc[nt - ntb][r] * 0.25f + bc;
          vv = (vv > 0.f) ? vv : (__expf(vv) - 1.f);   // ELU
          As[(mw + rq + r) * LDA2 + c] = f2bf_s(vv);
        }
      }
    }
  }
  __syncthreads();

  // ====== L2 phase 1: xl2 = As @ W2t -> xs^T; wave 0 adds logit tile ======
  {
    const int n0 = wv * 64;
    frag_cd acc[4][4] = {};
    frag_cd accL[4] = {};
#pragma unroll
    for (int ks = 0; ks < 128; ks += 32) {
      frag_ab b[4];
#pragma unroll
      for (int nt = 0; nt < 4; ++nt)
        b[nt] = *(const frag_ab*)((const short*)W2t +
                                  (size_t)(n0 + nt * 16 + lm) * W2T_K + ks + lk);
      frag_ab bl;
      if (wv == 0)
        bl = *(const frag_ab*)((const short*)W2t +
                               (size_t)(512 + lm) * W2T_K + ks + lk);
#pragma unroll
      for (int mt = 0; mt < 4; ++mt) {
        frag_ab a = *(const frag_ab*)&As[(mt * 16 + lm) * LDA2 + ks + lk];
#pragma unroll
        for (int nt = 0; nt < 4; ++nt)
          acc[mt][nt] = __builtin_amdgcn_mfma_f32_16x16x32_bf16(a, b[nt],
                                                                acc[mt][nt], 0, 0, 0);
        if (wv == 0)
          accL[mt] = __builtin_amdgcn_mfma_f32_16x16x32_bf16(a, bl, accL[mt], 0, 0, 0);
      }
    }
#pragma unroll
    for (int mt = 0; mt < 4; ++mt)
#pragma unroll
      for (int nt = 0; nt < 4; ++nt) {
        const int c4 = n0 + nt * 16 + lm;
        us4 o;
#pragma unroll
        for (int r = 0; r < 4; ++r) o[r] = (unsigned short)f2bf_s(acc[mt][nt][r]);
        *(us4*)&xs[c4 * LDT + mt * 16 + rq] = o;
      }
    if (wv == 0) {
#pragma unroll
      for (int mt = 0; mt < 4; ++mt) {
        us4 o;
#pragma unroll
        for (int r = 0; r < 4; ++r) o[r] = (unsigned short)f2bf_s(accL[mt][r]);
        *(us4*)&xs[(512 + lm) * LDT + mt * 16 + rq] = o;
      }
    }
  }
  __syncthreads();

  // ====== L2 phase 2: softmax -> Ps (same nonzero support; no re-zero) ======
  if (t < 256) {
    const int n = t >> 2, h = t & 3;
    const float ad = us2f(xs[(516 + h) * LDT + n]);
    int   sv[9];
    float a[9];
#pragma unroll
    for (int j = 0; j < 8; ++j) sv[j] = edg[n * DEG + j];
    sv[8] = n;
#pragma unroll
    for (int j = 0; j < 9; ++j) {
      float v = us2f(xs[(512 + h) * LDT + sv[j]]) + ad;
      a[j] = (v >= 0.f) ? v : 0.2f * v;
    }
    float m = -1e30f;
#pragma unroll
    for (int j = 0; j < 9; ++j) m = fmaxf(m, a[j]);
    float s = 0.f;
#pragma unroll
    for (int j = 0; j < 9; ++j) { a[j] = __expf(a[j] - m); s += a[j]; }
    const float inv = 1.f / (s + 1e-16f);
    short* prow = &Ps[(h * 64 + n) * LDT];
#pragma unroll
    for (int j = 0; j < 9; ++j) {
      float tw = a[j];
#pragma unroll
      for (int i = 0; i < 9; ++i)
        if (i != j && sv[i] == sv[j]) tw += a[i];
      prow[sv[j]] = f2bf_s(tw * inv);
    }
  }
  __syncthreads();

  // ====== L2 phase 3: h2 = 0.25*sum_h P_h @ X_h + bias -> h2t[k][b][c] ======
  {
    const int mw = (wv & 3) * 16;
    const int cg = wv >> 2;
    const int ntb = cg * 4;                    // NT=8 split 4+4
    frag_cd acc[4] = {};
#pragma unroll
    for (int h = 0; h < NHEADS; ++h)
#pragma unroll
      for (int ks = 0; ks < 64; ks += 32) {
        frag_ab a = *(const frag_ab*)&Ps[(h * 64 + mw + lm) * LDT + ks + lk];
#pragma unroll
        for (int nt = 0; nt < 4; ++nt) {
          frag_ab b = *(const frag_ab*)&xs[(h * C2 + (ntb + nt) * 16 + lm) * LDT + ks + lk];
          acc[nt] = __builtin_amdgcn_mfma_f32_16x16x32_bf16(a, b, acc[nt], 0, 0, 0);
        }
      }
    unsigned short* outp = (unsigned short*)h2t;
#pragma unroll
    for (int nt = 0; nt < 4; ++nt) {
      const int c = (ntb + nt) * 16 + lm;
      const float bc = bia2[c];
#pragma unroll
      for (int r = 0; r < 4; ++r) {
        float vv = acc[nt][r] * 0.25f + bc;
        outp[((size_t)(mw + rq + r) * B_GRAPHS + g) * C2 + c] =
            (unsigned short)f2bf_s(vv);
      }
    }
  }
}

// ---------------------------------------------------------------------------
// MFMA MLP head v2: A-frags direct from global h2t (contiguous per block),
// B-frags direct from global fw1t/fw2t (prepacked bf16, L2-resident).
// No input staging, one barrier. Grid 256 = (k) x (ms).
// ---------------------------------------------------------------------------
__global__ __launch_bounds__(256)
void mlp_mfma(const bf16* __restrict__ h2t,
              const bf16* __restrict__ fw1t, const float* __restrict__ fb1,
              const bf16* __restrict__ fw2t, const float* __restrict__ fb2,
              float* __restrict__ pred) {
  constexpr int LDH = HID + 8;   // 72
  __shared__ __align__(16) short Hs[64 * LDH];

  const int k  = blockIdx.x & 63;
  const int ms = blockIdx.x >> 6;
  const int t  = threadIdx.x;
  const int wv = t >> 6;
  const int l  = t & 63;
  const int lm = l & 15;
  const int lk = (l >> 4) * 8;
  const int rq = (l >> 4) * 4;

  const unsigned short* A  = (const unsigned short*)h2t +
                             ((size_t)k * B_GRAPHS + ms * 64) * C2;
  const unsigned short* B1 = (const unsigned short*)fw1t + (size_t)k * (HID * C2);

  frag_cd acc[4] = {};
#pragma unroll
  for (int ks = 0; ks < C2; ks += 32) {
    frag_ab a = *(const frag_ab*)(A + (size_t)(wv * 16 + lm) * C2 + ks + lk);
#pragma unroll
    for (int nt = 0; nt < 4; ++nt) {
      frag_ab b = *(const frag_ab*)(B1 + (size_t)(nt * 16 + lm) * C2 + ks + lk);
      acc[nt] = __builtin_amdgcn_mfma_f32_16x16x32_bf16(a, b, acc[nt], 0, 0, 0);
    }
  }
#pragma unroll
  for (int nt = 0; nt < 4; ++nt) {
    const int j  = nt * 16 + lm;
    const float bj = fb1[k * HID + j];
#pragma unroll
    for (int r = 0; r < 4; ++r) {
      const int m = wv * 16 + rq + r;
      Hs[m * LDH + j] = f2bf_s(fmaxf(acc[nt][r] + bj, 0.f));
    }
  }
  __syncthreads();

  const unsigned short* B2 = (const unsigned short*)fw2t + (size_t)k * (32 * HID);
  frag_cd acc2[2] = {};
#pragma unroll
  for (int ks = 0; ks < HID; ks += 32) {
    frag_ab a = *(const frag_ab*)&Hs[(wv * 16 + lm) * LDH + ks + lk];
#pragma unroll
    for (int nt = 0; nt < 2; ++nt) {
      frag_ab b = *(const frag_ab*)(B2 + (size_t)(nt * 16 + lm) * HID + ks + lk);
      acc2[nt] = __builtin_amdgcn_mfma_f32_16x16x32_bf16(a, b, acc2[nt], 0, 0, 0);
    }
  }
#pragma unroll
  for (int nt = 0; nt < 2; ++nt) {
    const int q = nt * 16 + lm;
    if (q < OUT_SZ) {
      const float bq = fb2[k * OUT_SZ + q];
#pragma unroll
      for (int r = 0; r < 4; ++r) {
        const int m = wv * 16 + rq + r;
        pred[((size_t)k * B_GRAPHS + ms * 64 + m) * OUT_SZ + q] = acc2[nt][r] + bq;
      }
    }
  }
}

// ---------------------------------------------------------------------------
extern "C" void kernel_launch(void* const* d_in, const int* in_sizes, int n_in,
                              void* d_out, int out_size, void* d_ws, size_t ws_size,
                              hipStream_t stream) {
  const float* x   = (const float*)d_in[0];
  const int*   ei  = (const int*)d_in[1];    // [2,E]: first E entries = src
  const float* y   = (const float*)d_in[3];
  const float* W1  = (const float*)d_in[4];
  const float* as1 = (const float*)d_in[5];
  const float* ad1 = (const float*)d_in[6];
  const float* b1  = (const float*)d_in[7];
  const float* W2  = (const float*)d_in[8];
  const float* as2 = (const float*)d_in[9];
  const float* ad2 = (const float*)d_in[10];
  const float* b2  = (const float*)d_in[11];
  const float* fw1 = (const float*)d_in[12];
  const float* fb1 = (const float*)d_in[13];
  const float* fw2 = (const float*)d_in[14];
  const float* fb2 = (const float*)d_in[15];

  // Workspace: h2t, W1t, W2t, fw1t, fw2t  (~5.7 MB)
  bf16* h2t  = (bf16*)d_ws;
  bf16* W1t  = h2t + (size_t)N_NODES * C2;
  bf16* W2t  = W1t + P1N;
  bf16* fw1t = W2t + P2N;
  bf16* fw2t = fw1t + FW1N;

  float* out = (float*)d_out;

  // ---- prep: pack W^T (+ fused attention-projection cols), fw^T, yg ----
  prep<<<(PREP_TOT + 255) / 256, 256, 0, stream>>>(
      W1, W2, y, as1, ad1, as2, ad2, fw1, fw2, W1t, W2t, fw1t, fw2t,
      out + PRED_ELEMS);

  // ---- fused two-layer GAT -> h2t (transposed by node index) ----
  gat_fused<<<B_GRAPHS, 512, 0, stream>>>(x, W1t, W2t, ei, b1, b2, h2t);

  // ---- MFMA MLP head -> pred (chunk0, f32) ----
  mlp_mfma<<<K_NODES * 4, 256, 0, stream>>>(h2t, fw1t, fb1, fw2t, fb2, out);
}